// Round 1
// baseline (148.926 us; speedup 1.0000x reference)
//
#include <hip/hip_runtime.h>

#define B 16384
#define N_SPARSE 16
#define N_VARLEN 4
#define L 50
#define V 1000000
#define ROW (N_SPARSE + N_VARLEN * L)   // 216 ids per row
#define OUT_W (N_SPARSE + N_VARLEN)     // 20 floats per row
#define KLANES 8                        // lanes cooperating per (row, varlen feature)

__global__ __launch_bounds__(256) void emb_gather_pool_kernel(
    const int* __restrict__ X,
    const float* __restrict__ sparse_tables,
    const float* __restrict__ varlen_tables,
    float* __restrict__ out)
{
    const int tid = blockIdx.x * blockDim.x + threadIdx.x;
    const int SPARSE_THREADS = B * N_SPARSE;            // 262144

    if (tid < SPARSE_THREADS) {
        // One thread per (row, sparse feature): single random gather.
        const int b = tid >> 4;        // /16
        const int j = tid & 15;
        const int id = X[b * ROW + j];
        out[b * OUT_W + j] = sparse_tables[(long)j * V + id];
    } else {
        // 8 lanes per (row, varlen feature) pooling task.
        const int t    = tid - SPARSE_THREADS;          // [0, B*4*8)
        const int lane = t & (KLANES - 1);
        const int task = t >> 3;                        // [0, B*4)
        const int f    = task & (N_VARLEN - 1);
        const int b    = task >> 2;

        const int*   ids = X + b * ROW + N_SPARSE + f * L;
        const float* tab = varlen_tables + (long)f * V;

        float sum = 0.0f;
        float cnt = 0.0f;
        #pragma unroll
        for (int l = lane; l < L; l += KLANES) {
            const int id = ids[l];
            const float v = tab[id];
            const float m = (id != 0) ? 1.0f : 0.0f;
            sum = fmaf(m, v, sum);
            cnt += m;
        }

        // Reduce across the aligned 8-lane group.
        #pragma unroll
        for (int off = 1; off < KLANES; off <<= 1) {
            sum += __shfl_xor(sum, off);
            cnt += __shfl_xor(cnt, off);
        }

        if (lane == 0) {
            out[b * OUT_W + N_SPARSE + f] = sum / (cnt + 1e-8f);
        }
    }
}

extern "C" void kernel_launch(void* const* d_in, const int* in_sizes, int n_in,
                              void* d_out, int out_size, void* d_ws, size_t ws_size,
                              hipStream_t stream) {
    const int*   X             = (const int*)  d_in[0];
    const float* sparse_tables = (const float*)d_in[1];
    const float* varlen_tables = (const float*)d_in[2];
    float*       out           = (float*)d_out;

    const int total_threads = B * N_SPARSE + B * N_VARLEN * KLANES; // 262144 + 524288
    const int block = 256;
    const int grid  = (total_threads + block - 1) / block;          // 3072

    emb_gather_pool_kernel<<<grid, block, 0, stream>>>(X, sparse_tables, varlen_tables, out);
}

// Round 2
// 129.535 us; speedup vs baseline: 1.1497x; 1.1497x over previous
//
#include <hip/hip_runtime.h>

#define B 16384
#define N_SPARSE 16
#define N_VARLEN 4
#define L 50
#define V 1000000
#define ROW (N_SPARSE + N_VARLEN * L)   // 216 ids per row
#define OUT_W (N_SPARSE + N_VARLEN)     // 20 floats per row
#define KLANES 8                        // lanes cooperating per (row, varlen feature)

// Grid layout (XCD = blockIdx % 8 on MI355X, 8 XCDs):
//   blocks [0, 2048):    varlen pooling. xcd = bid&7 -> feature f = xcd&3,
//                        row-half = xcd>>2. Each XCD's 4MB L2 caches exactly
//                        one 4MB varlen table, warm across graph replays.
//   blocks [2048, 3072): sparse gathers, 16 rows x 16 features per block,
//                        all traffic non-temporal (no L2 pollution).
#define VARLEN_BLOCKS 2048
#define SPARSE_BLOCKS 1024

__global__ __launch_bounds__(256) void emb_gather_pool_kernel(
    const int* __restrict__ X,
    const float* __restrict__ sparse_tables,
    const float* __restrict__ varlen_tables,
    float* __restrict__ out)
{
    const int bid = blockIdx.x;
    const int t   = threadIdx.x;

    if (bid < VARLEN_BLOCKS) {
        // ---- varlen masked-mean pooling, XCD-pinned per table ----
        const int xcd  = bid & 7;
        const int f    = xcd & 3;        // table f on XCDs f and f+4
        const int half = xcd >> 2;       // which half of the rows
        const int slot = bid >> 3;       // [0,256) row-chunk within (f, half)
        const int task = t >> 3;         // [0,32) row within block
        const int lane = t & (KLANES - 1);
        const int row  = half * (B / 2) + slot * 32 + task;

        const int*   ids = X + row * ROW + N_SPARSE + f * L;
        const float* tab = varlen_tables + (long)f * V;

        float sum = 0.0f;
        float cnt = 0.0f;
        #pragma unroll
        for (int l = lane; l < L; l += KLANES) {
            const int id = __builtin_nontemporal_load(ids + l);  // streamed once
            const float v = tab[id];                              // keep in L2!
            const float m = (id != 0) ? 1.0f : 0.0f;
            sum = fmaf(m, v, sum);
            cnt += m;
        }

        #pragma unroll
        for (int off = 1; off < KLANES; off <<= 1) {
            sum += __shfl_xor(sum, off);
            cnt += __shfl_xor(cnt, off);
        }

        if (lane == 0) {
            __builtin_nontemporal_store(sum / (cnt + 1e-8f),
                                        out + row * OUT_W + N_SPARSE + f);
        }
    } else {
        // ---- sparse single gathers, fully streaming (non-temporal) ----
        const int sb  = bid - VARLEN_BLOCKS;   // [0,1024)
        const int rl  = t >> 4;                // row within block [0,16)
        const int j   = t & 15;                // sparse feature
        const int row = sb * 16 + rl;

        const int   id = __builtin_nontemporal_load(X + row * ROW + j);
        const float v  = __builtin_nontemporal_load(sparse_tables + (long)j * V + id);
        __builtin_nontemporal_store(v, out + row * OUT_W + j);
    }
}

extern "C" void kernel_launch(void* const* d_in, const int* in_sizes, int n_in,
                              void* d_out, int out_size, void* d_ws, size_t ws_size,
                              hipStream_t stream) {
    const int*   X             = (const int*)  d_in[0];
    const float* sparse_tables = (const float*)d_in[1];
    const float* varlen_tables = (const float*)d_in[2];
    float*       out           = (float*)d_out;

    const int grid  = VARLEN_BLOCKS + SPARSE_BLOCKS;   // 3072
    const int block = 256;

    emb_gather_pool_kernel<<<grid, block, 0, stream>>>(X, sparse_tables, varlen_tables, out);
}